// Round 11
// baseline (148.962 us; speedup 1.0000x reference)
//
#include <hip/hip_runtime.h>
#include <hip/hip_bf16.h>
#include <math.h>

#define NE 8
#define DD 1024
#define HH 2048
#define NTOK 1024
#define NSLOT 2048
#define NSLOTP 3072

typedef short short8v __attribute__((ext_vector_type(8)));
typedef float f32x4 __attribute__((ext_vector_type(4)));

static __device__ __forceinline__ unsigned short f2bf(float f) {
  union { __hip_bfloat16 h; unsigned short u; } c;
  c.h = __float2bfloat16(f);
  return c.u;
}

static __device__ __forceinline__ short8v pk8(const float* q) {
  short8v v;
#pragma unroll
  for (int i = 0; i < 8; ++i) v[i] = (short)f2bf(q[i]);
  return v;
}

// raw barrier: drains LDS ops only (cross-wave visibility); global-load
// prefetches stay in flight across it.
static __device__ __forceinline__ void barrier_lds() {
  asm volatile("s_waitcnt lgkmcnt(0)" ::: "memory");
  __builtin_amdgcn_s_barrier();
  asm volatile("" ::: "memory");
}

// ---------------------------------------------------------------------------
// Router: one wave per token, exact f32, softmax over 8, top-2. [verified]
// ---------------------------------------------------------------------------
__global__ __launch_bounds__(64) void krouter(const float* __restrict__ x,
                                              const float* __restrict__ gw,
                                              int* __restrict__ e_sel,
                                              float* __restrict__ w_sel) {
  int n = blockIdx.x;
  int lane = threadIdx.x;
  const float4* xr = (const float4*)(x + (size_t)n * DD);
  const float4* gr = (const float4*)gw;
  float acc[NE];
#pragma unroll
  for (int e = 0; e < NE; ++e) acc[e] = 0.f;
#pragma unroll
  for (int i = 0; i < 4; ++i) {
    float4 xv = xr[lane + i * 64];
#pragma unroll
    for (int e = 0; e < NE; ++e) {
      float4 gv = gr[e * 256 + lane + i * 64];
      acc[e] += xv.x * gv.x + xv.y * gv.y + xv.z * gv.z + xv.w * gv.w;
    }
  }
#pragma unroll
  for (int e = 0; e < NE; ++e)
#pragma unroll
    for (int off = 32; off > 0; off >>= 1) acc[e] += __shfl_xor(acc[e], off);
  if (lane == 0) {
    float m = acc[0];
#pragma unroll
    for (int e = 1; e < NE; ++e) m = fmaxf(m, acc[e]);
    float p[NE];
    float z = 0.f;
#pragma unroll
    for (int e = 0; e < NE; ++e) { p[e] = expf(acc[e] - m); z += p[e]; }
    float inv = 1.f / z;
    int e1 = 0;
#pragma unroll
    for (int e = 1; e < NE; ++e) if (acc[e] > acc[e1]) e1 = e;
    int e2 = (e1 == 0) ? 1 : 0;
#pragma unroll
    for (int e = 0; e < NE; ++e) if (e != e1 && acc[e] > acc[e2]) e2 = e;
    e_sel[n] = e1;         w_sel[n] = p[e1] * inv;
    e_sel[NTOK + n] = e2;  w_sel[NTOK + n] = p[e2] * inv;
  }
}

// ---------------------------------------------------------------------------
// Build per-expert token lists (segments padded to 128) + compact tile maps.
// meta: [0:8) counts, [8:16) startp, [16] n64, [17] n128,
//       [32:80) t64e, [80:128) t64m, [128:152) t128e, [152:176) t128m
// ---------------------------------------------------------------------------
__global__ __launch_bounds__(256) void kbuild(const int* __restrict__ e_sel,
                                              const float* __restrict__ w_sel,
                                              int* __restrict__ tok,
                                              float* __restrict__ wgt,
                                              int* __restrict__ meta) {
  __shared__ int sc[NE], scur[NE];
  int t = threadIdx.x;
  if (t < NE) sc[t] = 0;
  __syncthreads();
  for (int s = t; s < NSLOTP; s += 256) tok[s] = -1;
  for (int s = t; s < NSLOT; s += 256) atomicAdd(&sc[e_sel[s]], 1);
  __syncthreads();
  if (t == 0) {
    int run = 0, i64 = 0, i128 = 0;
    for (int e = 0; e < NE; ++e) {
      meta[8 + e] = run; scur[e] = run;
      meta[e] = sc[e];
      int nm = (sc[e] + 127) >> 7;
      for (int m = 0; m < nm; ++m) {
        meta[128 + i128] = e; meta[152 + i128] = m; ++i128;
      }
      for (int m = 0; m < 2 * nm; ++m) {
        meta[32 + i64] = e; meta[80 + i64] = m; ++i64;
      }
      run += nm << 7;
    }
    meta[16] = i64; meta[17] = i128;
  }
  __syncthreads();
  for (int s = t; s < NSLOT; s += 256) {
    int e = e_sel[s];
    int pos = atomicAdd(&scur[e], 1);
    tok[pos] = s & (NTOK - 1);
    wgt[pos] = w_sel[s];
  }
}

// ---------------------------------------------------------------------------
// Gather+convert x -> xg[NSLOTP][1024] bf16, natural layout. Pad rows zeroed.
// ---------------------------------------------------------------------------
__global__ __launch_bounds__(256) void kgather(const float* __restrict__ x,
                                               const int* __restrict__ tok,
                                               unsigned short* __restrict__ xg) {
  int tid = threadIdx.x;
  int row = blockIdx.x * 2 + (tid >> 7);
  int g = tid & 127;
  int t = tok[row];
  char* dst = (char*)xg + (size_t)row * 2048 + (g << 4);
  short8v v = {0, 0, 0, 0, 0, 0, 0, 0};
  if (t >= 0) {
    const float* src = x + (size_t)t * DD + g * 8;
    float q[8];
#pragma unroll
    for (int i = 0; i < 8; ++i) q[i] = src[i];
    v = pk8(q);
  }
  *(short8v*)dst = v;
}

// ---------------------------------------------------------------------------
// GEMM1+3 fused: h = silu(X@w1)*(X@w3). BM=128 BN=64 BK=32, 4 waves 2x2.
// A: DIRECT global->reg from xg (1-step prefetch; L1/L2-hot, 16 full 64B
// lines per instr). B: coalesced f32 column loads, 3 register sets loaded
// 3 steps ahead (counted-vmcnt, no drain), cvt -> double-buffered LDS
// [64n x 64B] XOR-slot layout (r9-verified conflict-free). One lgkm-only
// barrier per step. All buffer/set indices compile-time (6-step rotation).
// ---------------------------------------------------------------------------
__global__ __launch_bounds__(256, 2) void kgemm13(
    const unsigned short* __restrict__ xg, const float* __restrict__ w1,
    const float* __restrict__ w3, unsigned short* __restrict__ hws,
    const int* __restrict__ meta) {
  __shared__ __align__(16) char smem[16384];  // B dbuf: buf*8192 + mat*4096
  char* ldsB = smem;
  int vt = blockIdx.y;
  if (vt >= meta[17]) return;
  int e = meta[128 + vt], mt = meta[152 + vt];
  int n0 = blockIdx.x * 64;
  int abase = meta[8 + e] + mt * 128;
  int tid = threadIdx.x, l = tid & 63, w = tid >> 6;
  int wm = w & 1, wn = w >> 1;

  // B staging: thread covers column n0+bn, k-octet kb.
  int bn = tid & 63, kb = tid >> 6;
  const float* pb1 = w1 + (size_t)e * DD * HH + (size_t)(kb * 8) * HH + n0 + bn;
  const float* pb3 = w3 + (size_t)e * DD * HH + (size_t)(kb * 8) * HH + n0 + bn;
  int wbB = bn * 64 + (((kb ^ (bn >> 1)) & 3) << 4);

  // A fragment sources (natural xg): row abase+wm*64+mf*16+(l&15), chunk l>>4.
  const char* pa[4];
#pragma unroll
  for (int mf = 0; mf < 4; ++mf) {
    int r = wm * 64 + mf * 16 + (l & 15);
    pa[mf] = (const char*)xg + (size_t)(abase + r) * 2048 + ((l >> 4) << 4);
  }
  // B fragment LDS offsets.
  int bfo[2];
#pragma unroll
  for (int nf = 0; nf < 2; ++nf) {
    int n = wn * 32 + nf * 16 + (l & 15);
    bfo[nf] = n * 64 + ((((l >> 4) ^ (n >> 1)) & 3) << 4);
  }

  f32x4 accg[4][2], accu[4][2];
#pragma unroll
  for (int i = 0; i < 4; ++i)
#pragma unroll
    for (int j = 0; j < 2; ++j) {
      accg[i][j] = (f32x4){0.f, 0.f, 0.f, 0.f};
      accu[i][j] = (f32x4){0.f, 0.f, 0.f, 0.f};
    }

  float q1_0[8], q3_0[8], q1_1[8], q3_1[8], q1_2[8], q3_2[8];
  short8v aA[4], aB[4];
  // ---- prologue: A(0); q(0),q(1),q(2); write B(0); barrier ----
#pragma unroll
  for (int mf = 0; mf < 4; ++mf) aA[mf] = *(const short8v*)(pa[mf]);
#pragma unroll
  for (int j = 0; j < 8; ++j) {
    q1_0[j] = pb1[(size_t)j * HH];          q3_0[j] = pb3[(size_t)j * HH];
    q1_1[j] = pb1[(size_t)(32 + j) * HH];   q3_1[j] = pb3[(size_t)(32 + j) * HH];
    q1_2[j] = pb1[(size_t)(64 + j) * HH];   q3_2[j] = pb3[(size_t)(64 + j) * HH];
  }
  *(short8v*)(ldsB + wbB) = pk8(q1_0);
  *(short8v*)(ldsB + 4096 + wbB) = pk8(q3_0);
  barrier_lds();

  // STEP(S): {B frag reads buf BUF} {A(S+1)->AN} {q(S+3)->QN} {MFMA(AC)}
  //          {write B(S+1) buf BUF^1 from QW (2 steps old)} {barrier}
#define STEP13(S, BUF, QW1, QW3, QN1, QN3, AC, AN, WR)                         \
  {                                                                            \
    short8v b1f[2], b3f[2];                                                    \
    _Pragma("unroll") for (int nf = 0; nf < 2; ++nf) {                         \
      b1f[nf] = *(const short8v*)(ldsB + (BUF) * 8192 + bfo[nf]);              \
      b3f[nf] = *(const short8v*)(ldsB + (BUF) * 8192 + 4096 + bfo[nf]);       \
    }                                                                          \
    if (WR) {                                                                  \
      _Pragma("unroll") for (int mf = 0; mf < 4; ++mf)                         \
          AN[mf] = *(const short8v*)(pa[mf] + ((S) + 1) * 64);                 \
    }                                                                          \
    if ((S) <= 28) {                                                           \
      size_t ko = (size_t)((S) + 3) * 32 * HH;                                 \
      _Pragma("unroll") for (int j = 0; j < 8; ++j) {                          \
        QN1[j] = pb1[ko + (size_t)j * HH];                                     \
        QN3[j] = pb3[ko + (size_t)j * HH];                                     \
      }                                                                        \
    }                                                                          \
    _Pragma("unroll") for (int nf = 0; nf < 2; ++nf)                           \
        _Pragma("unroll") for (int mf = 0; mf < 4; ++mf) {                     \
      accg[mf][nf] = __builtin_amdgcn_mfma_f32_16x16x32_bf16(                  \
          AC[mf], b1f[nf], accg[mf][nf], 0, 0, 0);                             \
      accu[mf][nf] = __builtin_amdgcn_mfma_f32_16x16x32_bf16(                  \
          AC[mf], b3f[nf], accu[mf][nf], 0, 0, 0);                             \
    }                                                                          \
    if (WR) {                                                                  \
      char* d = ldsB + (((BUF) ^ 1) * 8192);                                   \
      *(short8v*)(d + wbB) = pk8(QW1);                                         \
      *(short8v*)(d + 4096 + wbB) = pk8(QW3);                                  \
      barrier_lds();                                                           \
    }                                                                          \
  }

  for (int ss = 0; ss < 5; ++ss) {
    int s0 = 6 * ss;
    STEP13(s0 + 0, 0, q1_1, q3_1, q1_0, q3_0, aA, aB, 1);
    STEP13(s0 + 1, 1, q1_2, q3_2, q1_1, q3_1, aB, aA, 1);
    STEP13(s0 + 2, 0, q1_0, q3_0, q1_2, q3_2, aA, aB, 1);
    STEP13(s0 + 3, 1, q1_1, q3_1, q1_0, q3_0, aB, aA, 1);
    STEP13(s0 + 4, 0, q1_2, q3_2, q1_1, q3_1, aA, aB, 1);
    STEP13(s0 + 5, 1, q1_0, q3_0, q1_2, q3_2, aB, aA, 1);
  }
  STEP13(30, 0, q1_1, q3_1, q1_0, q3_0, aA, aB, 1);
  STEP13(31, 1, q1_2, q3_2, q1_0, q3_0, aB, aA, 0);
#undef STEP13

  __syncthreads();  // full drain before LDS reuse
  // Epilogue: silu(g)*u -> bf16 -> LDS restage (128x64) -> hws natural store.
  unsigned short* hl = (unsigned short*)smem;
#pragma unroll
  for (int mf = 0; mf < 4; ++mf)
#pragma unroll
    for (int nf = 0; nf < 2; ++nf)
#pragma unroll
      for (int rr = 0; rr < 4; ++rr) {
        int row = wm * 64 + mf * 16 + ((l >> 4) << 2) + rr;
        int col = wn * 32 + nf * 16 + (l & 15);
        float gv = accg[mf][nf][rr], uv = accu[mf][nf][rr];
        hl[row * 64 + col] = f2bf((gv / (1.f + __expf(-gv))) * uv);
      }
  __syncthreads();
#pragma unroll
  for (int p = 0; p < 4; ++p) {
    int idx = p * 256 + tid;
    int row = idx >> 3, g = idx & 7;
    int dp = abase + row;
    *(short8v*)((char*)hws + (size_t)dp * 4096 + (size_t)n0 * 2 + (g << 4)) =
        *(const short8v*)((const char*)hl + row * 128 + (g << 4));
  }
}

// ---------------------------------------------------------------------------
// GEMM2: y = h @ w2 (*routing weight), atomic scatter. BM=128 BN=64 BK=32,
// K-split 2, 4 waves 2x2. Same structure, single B matrix (8KB LDS).
// ---------------------------------------------------------------------------
__global__ __launch_bounds__(256, 3) void kgemm2(
    const unsigned short* __restrict__ hws, const float* __restrict__ w2,
    float* __restrict__ out, const int* __restrict__ tok,
    const float* __restrict__ wgt, const int* __restrict__ meta) {
  __shared__ __align__(16) char smem[8192];  // B dbuf: buf*4096
  char* ldsB = smem;
  int vt = blockIdx.y;
  if (vt >= meta[17]) return;
  int e = meta[128 + vt], mt = meta[152 + vt];
  int n0 = blockIdx.x * 64;
  int kz = blockIdx.z;
  int mbase = meta[8 + e] + mt * 128;
  int rem = meta[e] - mt * 128;
  int tid = threadIdx.x, l = tid & 63, w = tid >> 6;
  int wm = w & 1, wn = w >> 1;

  int bn = tid & 63, kb = tid >> 6;
  const float* pb = w2 + (size_t)e * HH * DD +
                    (size_t)(kz * 1024 + kb * 8) * DD + n0 + bn;
  int wbB = bn * 64 + (((kb ^ (bn >> 1)) & 3) << 4);

  const char* pa[4];
#pragma unroll
  for (int mf = 0; mf < 4; ++mf) {
    int r = wm * 64 + mf * 16 + (l & 15);
    pa[mf] = (const char*)hws + (size_t)(mbase + r) * 4096 + kz * 2048 +
             ((l >> 4) << 4);
  }
  int bfo[2];
#pragma unroll
  for (int nf = 0; nf < 2; ++nf) {
    int n = wn * 32 + nf * 16 + (l & 15);
    bfo[nf] = n * 64 + ((((l >> 4) ^ (n >> 1)) & 3) << 4);
  }

  f32x4 acc[4][2];
#pragma unroll
  for (int i = 0; i < 4; ++i)
#pragma unroll
    for (int j = 0; j < 2; ++j) acc[i][j] = (f32x4){0.f, 0.f, 0.f, 0.f};

  float q_0[8], q_1[8], q_2[8];
  short8v aA[4], aB[4];
#pragma unroll
  for (int mf = 0; mf < 4; ++mf) aA[mf] = *(const short8v*)(pa[mf]);
#pragma unroll
  for (int j = 0; j < 8; ++j) {
    q_0[j] = pb[(size_t)j * DD];
    q_1[j] = pb[(size_t)(32 + j) * DD];
    q_2[j] = pb[(size_t)(64 + j) * DD];
  }
  *(short8v*)(ldsB + wbB) = pk8(q_0);
  barrier_lds();

#define STEP2(S, BUF, QW, QN, AC, AN, WR)                                      \
  {                                                                            \
    short8v bf[2];                                                             \
    _Pragma("unroll") for (int nf = 0; nf < 2; ++nf)                           \
        bf[nf] = *(const short8v*)(ldsB + (BUF) * 4096 + bfo[nf]);             \
    if (WR) {                                                                  \
      _Pragma("unroll") for (int mf = 0; mf < 4; ++mf)                         \
          AN[mf] = *(const short8v*)(pa[mf] + ((S) + 1) * 64);                 \
    }                                                                          \
    if ((S) <= 28) {                                                           \
      size_t ko = (size_t)((S) + 3) * 32 * DD;                                 \
      _Pragma("unroll") for (int j = 0; j < 8; ++j)                            \
          QN[j] = pb[ko + (size_t)j * DD];                                     \
    }                                                                          \
    _Pragma("unroll") for (int nf = 0; nf < 2; ++nf)                           \
        _Pragma("unroll") for (int mf = 0; mf < 4; ++mf)                       \
            acc[mf][nf] = __builtin_amdgcn_mfma_f32_16x16x32_bf16(             \
                AC[mf], bf[nf], acc[mf][nf], 0, 0, 0);                         \
    if (WR) {                                                                  \
      *(short8v*)(ldsB + (((BUF) ^ 1) * 4096) + wbB) = pk8(QW);                \
      barrier_lds();                                                           \
    }                                                                          \
  }

  for (int ss = 0; ss < 5; ++ss) {
    int s0 = 6 * ss;
    STEP2(s0 + 0, 0, q_1, q_0, aA, aB, 1);
    STEP2(s0 + 1, 1, q_2, q_1, aB, aA, 1);
    STEP2(s0 + 2, 0, q_0, q_2, aA, aB, 1);
    STEP2(s0 + 3, 1, q_1, q_0, aB, aA, 1);
    STEP2(s0 + 4, 0, q_2, q_1, aA, aB, 1);
    STEP2(s0 + 5, 1, q_0, q_2, aB, aA, 1);
  }
  STEP2(30, 0, q_1, q_0, aA, aB, 1);
  STEP2(31, 1, q_2, q_0, aB, aA, 0);
#undef STEP2

#pragma unroll
  for (int mf = 0; mf < 4; ++mf)
#pragma unroll
    for (int rr = 0; rr < 4; ++rr) {
      int row = wm * 64 + mf * 16 + ((l >> 4) << 2) + rr;
      if (row < rem) {
        int t = tok[mbase + row];
        float wt = wgt[mbase + row];
#pragma unroll
        for (int nf = 0; nf < 2; ++nf)
          atomicAdd(out + (size_t)t * DD + n0 + wn * 32 + nf * 16 + (l & 15),
                    wt * acc[mf][nf][rr]);
      }
    }
}

// ---------------------------------------------------------------------------
extern "C" void kernel_launch(void* const* d_in, const int* in_sizes, int n_in,
                              void* d_out, int out_size, void* d_ws, size_t ws_size,
                              hipStream_t stream) {
  const float* x  = (const float*)d_in[0];
  const float* gw = (const float*)d_in[1];
  const float* w1 = (const float*)d_in[2];
  const float* w2 = (const float*)d_in[3];
  const float* w3 = (const float*)d_in[4];
  float* out = (float*)d_out;
  char* ws = (char*)d_ws;
  const size_t MB = 1024 * 1024;
  if (ws_size < 24 * MB) return;

  unsigned short* xg  = (unsigned short*)(ws);            // 6MB
  unsigned short* hws = (unsigned short*)(ws + 6 * MB);   // 12MB
  char* mb = ws + 20 * MB;
  int*   e_sel  = (int*)mb;
  float* w_sel  = (float*)(mb + 8192);
  int*   tok    = (int*)(mb + 16384);
  float* wgt    = (float*)(mb + 16384 + 12288);
  int*   meta   = (int*)(mb + 16384 + 24576);

  hipMemsetAsync(out, 0, (size_t)out_size * sizeof(float), stream);
  krouter<<<dim3(NTOK), 64, 0, stream>>>(x, gw, e_sel, w_sel);
  kbuild<<<1, 256, 0, stream>>>(e_sel, w_sel, tok, wgt, meta);
  kgather<<<dim3(NSLOTP / 2), 256, 0, stream>>>(x, tok, xg);
  kgemm13<<<dim3(32, 24), 256, 0, stream>>>(xg, w1, w3, hws, meta);
  kgemm2<<<dim3(16, 24, 2), 256, 0, stream>>>(hws, w2, out, tok, wgt, meta);
}

// Round 13
// 108.418 us; speedup vs baseline: 1.3740x; 1.3740x over previous
//
#include <hip/hip_runtime.h>
#include <hip/hip_bf16.h>
#include <math.h>

#define NE 8
#define DD 1024
#define HH 2048
#define NTOK 1024
#define NSLOT 2048
#define NSLOTP 3072

typedef short short8v __attribute__((ext_vector_type(8)));
typedef float f32x4 __attribute__((ext_vector_type(4)));

static __device__ __forceinline__ unsigned short f2bf(float f) {
  union { __hip_bfloat16 h; unsigned short u; } c;
  c.h = __float2bfloat16(f);
  return c.u;
}

static __device__ __forceinline__ short8v pk8(const float* q) {
  short8v v;
#pragma unroll
  for (int i = 0; i < 8; ++i) v[i] = (short)f2bf(q[i]);
  return v;
}

// raw barrier: drains LDS ops only (cross-wave visibility); global-load
// prefetches stay in flight across it. [passed replay-validation r9,r10]
static __device__ __forceinline__ void barrier_lds() {
  asm volatile("s_waitcnt lgkmcnt(0)" ::: "memory");
  __builtin_amdgcn_s_barrier();
  asm volatile("" ::: "memory");
}

// ---------------------------------------------------------------------------
// Router: one wave per token, exact f32, softmax over 8, top-2. [verified]
// ---------------------------------------------------------------------------
__global__ __launch_bounds__(64) void krouter(const float* __restrict__ x,
                                              const float* __restrict__ gw,
                                              int* __restrict__ e_sel,
                                              float* __restrict__ w_sel) {
  int n = blockIdx.x;
  int lane = threadIdx.x;
  const float4* xr = (const float4*)(x + (size_t)n * DD);
  const float4* gr = (const float4*)gw;
  float acc[NE];
#pragma unroll
  for (int e = 0; e < NE; ++e) acc[e] = 0.f;
#pragma unroll
  for (int i = 0; i < 4; ++i) {
    float4 xv = xr[lane + i * 64];
#pragma unroll
    for (int e = 0; e < NE; ++e) {
      float4 gv = gr[e * 256 + lane + i * 64];
      acc[e] += xv.x * gv.x + xv.y * gv.y + xv.z * gv.z + xv.w * gv.w;
    }
  }
#pragma unroll
  for (int e = 0; e < NE; ++e)
#pragma unroll
    for (int off = 32; off > 0; off >>= 1) acc[e] += __shfl_xor(acc[e], off);
  if (lane == 0) {
    float m = acc[0];
#pragma unroll
    for (int e = 1; e < NE; ++e) m = fmaxf(m, acc[e]);
    float p[NE];
    float z = 0.f;
#pragma unroll
    for (int e = 0; e < NE; ++e) { p[e] = expf(acc[e] - m); z += p[e]; }
    float inv = 1.f / z;
    int e1 = 0;
#pragma unroll
    for (int e = 1; e < NE; ++e) if (acc[e] > acc[e1]) e1 = e;
    int e2 = (e1 == 0) ? 1 : 0;
#pragma unroll
    for (int e = 0; e < NE; ++e) if (e != e1 && acc[e] > acc[e2]) e2 = e;
    e_sel[n] = e1;         w_sel[n] = p[e1] * inv;
    e_sel[NTOK + n] = e2;  w_sel[NTOK + n] = p[e2] * inv;
  }
}

// ---------------------------------------------------------------------------
// Build per-expert token lists (segments padded to 128) + compact tile maps.
// meta: [0:8) counts, [8:16) startp, [16] n64, [17] n128,
//       [32:80) t64e, [80:128) t64m, [128:152) t128e, [152:176) t128m
// ---------------------------------------------------------------------------
__global__ __launch_bounds__(256) void kbuild(const int* __restrict__ e_sel,
                                              const float* __restrict__ w_sel,
                                              int* __restrict__ tok,
                                              float* __restrict__ wgt,
                                              int* __restrict__ meta) {
  __shared__ int sc[NE], scur[NE];
  int t = threadIdx.x;
  if (t < NE) sc[t] = 0;
  __syncthreads();
  for (int s = t; s < NSLOTP; s += 256) tok[s] = -1;
  for (int s = t; s < NSLOT; s += 256) atomicAdd(&sc[e_sel[s]], 1);
  __syncthreads();
  if (t == 0) {
    int run = 0, i64 = 0, i128 = 0;
    for (int e = 0; e < NE; ++e) {
      meta[8 + e] = run; scur[e] = run;
      meta[e] = sc[e];
      int nm = (sc[e] + 127) >> 7;
      for (int m = 0; m < nm; ++m) {
        meta[128 + i128] = e; meta[152 + i128] = m; ++i128;
      }
      for (int m = 0; m < 2 * nm; ++m) {
        meta[32 + i64] = e; meta[80 + i64] = m; ++i64;
      }
      run += nm << 7;
    }
    meta[16] = i64; meta[17] = i128;
  }
  __syncthreads();
  for (int s = t; s < NSLOT; s += 256) {
    int e = e_sel[s];
    int pos = atomicAdd(&scur[e], 1);
    tok[pos] = s & (NTOK - 1);
    wgt[pos] = w_sel[s];
  }
}

// ---------------------------------------------------------------------------
// Gather+convert x -> xg[NSLOTP][1024] bf16, natural layout. Pad rows zeroed.
// ---------------------------------------------------------------------------
__global__ __launch_bounds__(256) void kgather(const float* __restrict__ x,
                                               const int* __restrict__ tok,
                                               unsigned short* __restrict__ xg) {
  int tid = threadIdx.x;
  int row = blockIdx.x * 2 + (tid >> 7);
  int g = tid & 127;
  int t = tok[row];
  char* dst = (char*)xg + (size_t)row * 2048 + (g << 4);
  short8v v = {0, 0, 0, 0, 0, 0, 0, 0};
  if (t >= 0) {
    const float* src = x + (size_t)t * DD + g * 8;
    float q[8];
#pragma unroll
    for (int i = 0; i < 8; ++i) q[i] = src[i];
    v = pk8(q);
  }
  *(short8v*)dst = v;
}

// ---------------------------------------------------------------------------
// GEMM1+3 fused: h = silu(X@w1)*(X@w3). BM=128 BN=64 BK=32, 4 waves 2x2
// (wave-tile 64m x 32n). Structure IDENTICAL to round-10 (replay-verified);
// only the LDS layout changed: pad-80 -> XOR-64B (slot = chunk ^ ((row>>1)&3),
// r9-measured 163K conflicts vs pad-80's 4.1M).
// ---------------------------------------------------------------------------
__global__ __launch_bounds__(256, 2) void kgemm13(
    const unsigned short* __restrict__ xg, const float* __restrict__ w1,
    const float* __restrict__ w3, unsigned short* __restrict__ hws,
    const int* __restrict__ meta) {
  __shared__ __align__(16) char smem[32768];
  char* ldsA = smem;              // buf*8192 + half*4096; row*64 + slot*16
  char* ldsB = smem + 16384;      // buf*8192 + mat*4096;  n*64  + slot*16
  int vt = blockIdx.y;
  if (vt >= meta[17]) return;
  int e = meta[128 + vt], mt = meta[152 + vt];
  int n0 = blockIdx.x * 64;
  int abase = meta[8 + e] + mt * 128;
  int tid = threadIdx.x, l = tid & 63, w = tid >> 6;
  int wm = w & 1, wn = w >> 1;

  // A staging: thread covers 16B chunk ag of row arow (and row arow+64).
  int arow = tid >> 2, ag = tid & 3;
  const char* paA = (const char*)xg + (size_t)(abase + arow) * 2048 + (ag << 4);
  int wbA = arow * 64 + (((ag ^ (arow >> 1)) & 3) << 4);
  // B staging: thread covers column n0+bn, k-octet kb (coalesced 256B rows).
  int bn = tid & 63, kb = tid >> 6;
  const float* pb1 = w1 + (size_t)e * DD * HH + (size_t)(kb * 8) * HH + n0 + bn;
  const float* pb3 = w3 + (size_t)e * DD * HH + (size_t)(kb * 8) * HH + n0 + bn;
  int wbB = bn * 64 + (((kb ^ (bn >> 1)) & 3) << 4);

  // fragment LDS offsets (match XOR layout)
  int afo[4];
#pragma unroll
  for (int mf = 0; mf < 4; ++mf) {
    int r = wm * 64 + mf * 16 + (l & 15);
    afo[mf] = r * 64 + ((((l >> 4) ^ (r >> 1)) & 3) << 4);
  }
  int bfo[2];
#pragma unroll
  for (int nf = 0; nf < 2; ++nf) {
    int n = wn * 32 + nf * 16 + (l & 15);
    bfo[nf] = n * 64 + ((((l >> 4) ^ (n >> 1)) & 3) << 4);
  }

  f32x4 accg[4][2], accu[4][2];
#pragma unroll
  for (int i = 0; i < 4; ++i)
#pragma unroll
    for (int j = 0; j < 2; ++j) {
      accg[i][j] = (f32x4){0.f, 0.f, 0.f, 0.f};
      accu[i][j] = (f32x4){0.f, 0.f, 0.f, 0.f};
    }

  float q1A[8], q3A[8], q1B[8], q3B[8];
  short8v aqA[2], aqB[2];
  // ---- prologue: q(0)->A set, write staging(0) buf0, q(1)->B set ----
  aqA[0] = *(const short8v*)(paA);
  aqA[1] = *(const short8v*)(paA + 131072);
#pragma unroll
  for (int j = 0; j < 8; ++j) {
    q1A[j] = pb1[(size_t)j * HH];
    q3A[j] = pb3[(size_t)j * HH];
  }
  *(short8v*)(ldsA + wbA) = aqA[0];
  *(short8v*)(ldsA + 4096 + wbA) = aqA[1];
  *(short8v*)(ldsB + wbB) = pk8(q1A);
  *(short8v*)(ldsB + 4096 + wbB) = pk8(q3A);
  aqB[0] = *(const short8v*)(paA + 64);
  aqB[1] = *(const short8v*)(paA + 131072 + 64);
#pragma unroll
  for (int j = 0; j < 8; ++j) {
    q1B[j] = pb1[(size_t)(32 + j) * HH];
    q3B[j] = pb3[(size_t)(32 + j) * HH];
  }
  barrier_lds();

  // STEP(S): frag-read buf S&1 -> MFMA; write staging(S+1) from W-set;
  // load q(S+2) into N-set; one lgkm barrier.  [round-10 order, verbatim]
#define STEP13(S, QW1, QW3, AQW, QN1, QN3, AQN)                                \
  {                                                                            \
    int bo = ((S) & 1) * 8192;                                                 \
    short8v af[4], b1f[2], b3f[2];                                             \
    _Pragma("unroll") for (int mf = 0; mf < 4; ++mf)                           \
        af[mf] = *(const short8v*)(ldsA + bo + afo[mf]);                       \
    _Pragma("unroll") for (int nf = 0; nf < 2; ++nf) {                         \
      b1f[nf] = *(const short8v*)(ldsB + bo + bfo[nf]);                        \
      b3f[nf] = *(const short8v*)(ldsB + bo + 4096 + bfo[nf]);                 \
    }                                                                          \
    if ((S) < 31) {                                                            \
      int wo = (((S) + 1) & 1) * 8192;                                         \
      *(short8v*)(ldsA + wo + wbA) = AQW[0];                                   \
      *(short8v*)(ldsA + wo + 4096 + wbA) = AQW[1];                            \
      *(short8v*)(ldsB + wo + wbB) = pk8(QW1);                                 \
      *(short8v*)(ldsB + wo + 4096 + wbB) = pk8(QW3);                          \
    }                                                                          \
    if ((S) < 30) {                                                            \
      AQN[0] = *(const short8v*)(paA + ((S) + 2) * 64);                        \
      AQN[1] = *(const short8v*)(paA + 131072 + ((S) + 2) * 64);               \
      size_t ko = (size_t)((S) + 2) * 32 * HH;                                 \
      _Pragma("unroll") for (int j = 0; j < 8; ++j) {                          \
        QN1[j] = pb1[ko + (size_t)j * HH];                                     \
        QN3[j] = pb3[ko + (size_t)j * HH];                                     \
      }                                                                        \
    }                                                                          \
    _Pragma("unroll") for (int nf = 0; nf < 2; ++nf)                           \
        _Pragma("unroll") for (int mf = 0; mf < 4; ++mf) {                     \
      accg[mf][nf] = __builtin_amdgcn_mfma_f32_16x16x32_bf16(                  \
          af[mf], b1f[nf], accg[mf][nf], 0, 0, 0);                             \
      accu[mf][nf] = __builtin_amdgcn_mfma_f32_16x16x32_bf16(                  \
          af[mf], b3f[nf], accu[mf][nf], 0, 0, 0);                             \
    }                                                                          \
    if ((S) < 31) barrier_lds();                                               \
  }

  for (int ss = 0; ss < 16; ++ss) {
    int s0 = 2 * ss;
    STEP13(s0, q1B, q3B, aqB, q1A, q3A, aqA);
    STEP13(s0 + 1, q1A, q3A, aqA, q1B, q3B, aqB);
  }
#undef STEP13

  __syncthreads();  // full drain before LDS reuse
  // Epilogue: silu(g)*u -> bf16 -> LDS restage (128x64) -> hws natural store.
  unsigned short* hl = (unsigned short*)smem;
#pragma unroll
  for (int mf = 0; mf < 4; ++mf)
#pragma unroll
    for (int nf = 0; nf < 2; ++nf)
#pragma unroll
      for (int rr = 0; rr < 4; ++rr) {
        int row = wm * 64 + mf * 16 + ((l >> 4) << 2) + rr;
        int col = wn * 32 + nf * 16 + (l & 15);
        float gv = accg[mf][nf][rr], uv = accu[mf][nf][rr];
        hl[row * 64 + col] = f2bf((gv / (1.f + __expf(-gv))) * uv);
      }
  __syncthreads();
#pragma unroll
  for (int p = 0; p < 4; ++p) {
    int idx = p * 256 + tid;
    int row = idx >> 3, g = idx & 7;
    int dp = abase + row;
    *(short8v*)((char*)hws + (size_t)dp * 4096 + (size_t)n0 * 2 + (g << 4)) =
        *(const short8v*)((const char*)hl + row * 128 + (g << 4));
  }
}

// ---------------------------------------------------------------------------
// GEMM2: y = h @ w2 (*routing weight), atomic scatter. BM=128 BN=64 BK=32,
// K-split 2, 4 waves 2x2. Round-10 structure; XOR-64B layout only change.
// ---------------------------------------------------------------------------
__global__ __launch_bounds__(256, 3) void kgemm2(
    const unsigned short* __restrict__ hws, const float* __restrict__ w2,
    float* __restrict__ out, const int* __restrict__ tok,
    const float* __restrict__ wgt, const int* __restrict__ meta) {
  __shared__ __align__(16) char smem[24576];
  char* ldsA = smem;              // buf*8192 + half*4096
  char* ldsB = smem + 16384;      // buf*4096
  int vt = blockIdx.y;
  if (vt >= meta[17]) return;
  int e = meta[128 + vt], mt = meta[152 + vt];
  int n0 = blockIdx.x * 64;
  int kz = blockIdx.z;
  int mbase = meta[8 + e] + mt * 128;
  int rem = meta[e] - mt * 128;
  int tid = threadIdx.x, l = tid & 63, w = tid >> 6;
  int wm = w & 1, wn = w >> 1;

  int arow = tid >> 2, ag = tid & 3;
  const char* paA = (const char*)hws + (size_t)(mbase + arow) * 4096 +
                    kz * 2048 + (ag << 4);
  int wbA = arow * 64 + (((ag ^ (arow >> 1)) & 3) << 4);
  int bn = tid & 63, kb = tid >> 6;
  const float* pb = w2 + (size_t)e * HH * DD +
                    (size_t)(kz * 1024 + kb * 8) * DD + n0 + bn;
  int wbB = bn * 64 + (((kb ^ (bn >> 1)) & 3) << 4);

  int afo[4];
#pragma unroll
  for (int mf = 0; mf < 4; ++mf) {
    int r = wm * 64 + mf * 16 + (l & 15);
    afo[mf] = r * 64 + ((((l >> 4) ^ (r >> 1)) & 3) << 4);
  }
  int bfo[2];
#pragma unroll
  for (int nf = 0; nf < 2; ++nf) {
    int n = wn * 32 + nf * 16 + (l & 15);
    bfo[nf] = n * 64 + ((((l >> 4) ^ (n >> 1)) & 3) << 4);
  }

  f32x4 acc[4][2];
#pragma unroll
  for (int i = 0; i < 4; ++i)
#pragma unroll
    for (int j = 0; j < 2; ++j) acc[i][j] = (f32x4){0.f, 0.f, 0.f, 0.f};

  float qA[8], qB[8];
  short8v aqA[2], aqB[2];
  aqA[0] = *(const short8v*)(paA);
  aqA[1] = *(const short8v*)(paA + 262144);  // +64 rows * 4096
#pragma unroll
  for (int j = 0; j < 8; ++j) qA[j] = pb[(size_t)j * DD];
  *(short8v*)(ldsA + wbA) = aqA[0];
  *(short8v*)(ldsA + 4096 + wbA) = aqA[1];
  *(short8v*)(ldsB + wbB) = pk8(qA);
  aqB[0] = *(const short8v*)(paA + 64);
  aqB[1] = *(const short8v*)(paA + 262144 + 64);
#pragma unroll
  for (int j = 0; j < 8; ++j) qB[j] = pb[(size_t)(32 + j) * DD];
  barrier_lds();

#define STEP2(S, QW, AQW, QN, AQN)                                             \
  {                                                                            \
    int bo = ((S) & 1) * 8192;                                                 \
    int bob = ((S) & 1) * 4096;                                                \
    short8v af[4], bf[2];                                                      \
    _Pragma("unroll") for (int mf = 0; mf < 4; ++mf)                           \
        af[mf] = *(const short8v*)(ldsA + bo + afo[mf]);                       \
    _Pragma("unroll") for (int nf = 0; nf < 2; ++nf)                           \
        bf[nf] = *(const short8v*)(ldsB + bob + bfo[nf]);                      \
    if ((S) < 31) {                                                            \
      int wo = (((S) + 1) & 1) * 8192;                                         \
      int wob = (((S) + 1) & 1) * 4096;                                        \
      *(short8v*)(ldsA + wo + wbA) = AQW[0];                                   \
      *(short8v*)(ldsA + wo + 4096 + wbA) = AQW[1];                            \
      *(short8v*)(ldsB + wob + wbB) = pk8(QW);                                 \
    }                                                                          \
    if ((S) < 30) {                                                            \
      AQN[0] = *(const short8v*)(paA + ((S) + 2) * 64);                        \
      AQN[1] = *(const short8v*)(paA + 262144 + ((S) + 2) * 64);               \
      size_t ko = (size_t)((S) + 2) * 32 * DD;                                 \
      _Pragma("unroll") for (int j = 0; j < 8; ++j)                            \
          QN[j] = pb[ko + (size_t)j * DD];                                     \
    }                                                                          \
    _Pragma("unroll") for (int nf = 0; nf < 2; ++nf)                           \
        _Pragma("unroll") for (int mf = 0; mf < 4; ++mf)                       \
            acc[mf][nf] = __builtin_amdgcn_mfma_f32_16x16x32_bf16(             \
                af[mf], bf[nf], acc[mf][nf], 0, 0, 0);                         \
    if ((S) < 31) barrier_lds();                                               \
  }

  for (int ss = 0; ss < 16; ++ss) {
    int s0 = 2 * ss;
    STEP2(s0, qB, aqB, qA, aqA);
    STEP2(s0 + 1, qA, aqA, qB, aqB);
  }
#undef STEP2

#pragma unroll
  for (int mf = 0; mf < 4; ++mf)
#pragma unroll
    for (int rr = 0; rr < 4; ++rr) {
      int row = wm * 64 + mf * 16 + ((l >> 4) << 2) + rr;
      if (row < rem) {
        int t = tok[mbase + row];
        float wt = wgt[mbase + row];
#pragma unroll
        for (int nf = 0; nf < 2; ++nf)
          atomicAdd(out + (size_t)t * DD + n0 + wn * 32 + nf * 16 + (l & 15),
                    wt * acc[mf][nf][rr]);
      }
    }
}

// ---------------------------------------------------------------------------
extern "C" void kernel_launch(void* const* d_in, const int* in_sizes, int n_in,
                              void* d_out, int out_size, void* d_ws, size_t ws_size,
                              hipStream_t stream) {
  const float* x  = (const float*)d_in[0];
  const float* gw = (const float*)d_in[1];
  const float* w1 = (const float*)d_in[2];
  const float* w2 = (const float*)d_in[3];
  const float* w3 = (const float*)d_in[4];
  float* out = (float*)d_out;
  char* ws = (char*)d_ws;
  const size_t MB = 1024 * 1024;
  if (ws_size < 24 * MB) return;

  unsigned short* xg  = (unsigned short*)(ws);            // 6MB
  unsigned short* hws = (unsigned short*)(ws + 6 * MB);   // 12MB
  char* mb = ws + 20 * MB;
  int*   e_sel  = (int*)mb;
  float* w_sel  = (float*)(mb + 8192);
  int*   tok    = (int*)(mb + 16384);
  float* wgt    = (float*)(mb + 16384 + 12288);
  int*   meta   = (int*)(mb + 16384 + 24576);

  hipMemsetAsync(out, 0, (size_t)out_size * sizeof(float), stream);
  krouter<<<dim3(NTOK), 64, 0, stream>>>(x, gw, e_sel, w_sel);
  kbuild<<<1, 256, 0, stream>>>(e_sel, w_sel, tok, wgt, meta);
  kgather<<<dim3(NSLOTP / 2), 256, 0, stream>>>(x, tok, xg);
  kgemm13<<<dim3(32, 24), 256, 0, stream>>>(xg, w1, w3, hws, meta);
  kgemm2<<<dim3(16, 24, 2), 256, 0, stream>>>(hws, w2, out, tok, wgt, meta);
}